// Round 10
// baseline (84.419 us; speedup 1.0000x reference)
//
#include <hip/hip_runtime.h>
#include <math.h>

// BCE-with-logits + top-10% mean, shape (2,1,192,256,256) fp32.
// R10: two-phase decomposition. Phase A: pure stream read x,t -> compute
// loss -> write packed u8 bin indices (NB=256, 25 MB). No LDS, no atomics.
// Phase B: histogram the u8 bins (16 per 16B load, wave-private LDS).
// Finalize: 256-bin suffix scan. Worst-case bin-center error 1.56e-2
// < 3.08e-2 threshold (expected ~1e-3). Fallback fused path if ws small.

typedef float f4 __attribute__((ext_vector_type(4)));
typedef unsigned int u32;
typedef u32 u32x4 __attribute__((ext_vector_type(4)));

#define NB 256
#define ROWS 2
#define RANGE 8.0f
#define INV_BINW ((float)NB / RANGE)   // 32 bins per unit loss
#define BINW (RANGE / (float)NB)       // 0.03125
#define TPB 256
#define BPR 512            // blocks per row, phase A
#define BPRB 256           // blocks per row, phase B

__device__ __forceinline__ u32 pack_bins(const f4 xv, const f4 tv) {
    u32 w = 0;
    #pragma unroll
    for (int j = 0; j < 4; ++j) {
        float xs = xv[j], ts = tv[j];
        float l = __logf(1.0f + __expf(xs)) - xs * ts;   // loss >= 0
        int b = min(max((int)(l * INV_BINW), 0), NB - 1);
        w |= (u32)b << (8 * j);
    }
    return w;
}

// ---- Phase A: stream -> packed bin indices (no LDS, no atomics) ----
__global__ __launch_bounds__(TPB) void binize_kernel(
    const f4* __restrict__ x4g, const f4* __restrict__ t4g,
    u32* __restrict__ bins, int spatial4)
{
    const int row = blockIdx.y;
    const f4* __restrict__ x4 = x4g + (size_t)row * spatial4;
    const f4* __restrict__ t4 = t4g + (size_t)row * spatial4;
    u32* __restrict__ bo = bins + (size_t)row * spatial4;

    const int stride = BPR * TPB;
    int i = blockIdx.x * TPB + threadIdx.x;
    for (; i + 3 * stride < spatial4; i += 4 * stride) {
        f4 xa = x4[i];
        f4 xb = x4[i + stride];
        f4 xc = x4[i + 2 * stride];
        f4 xd = x4[i + 3 * stride];
        f4 ta = t4[i];
        f4 tb = t4[i + stride];
        f4 tc = t4[i + 2 * stride];
        f4 td = t4[i + 3 * stride];
        bo[i]              = pack_bins(xa, ta);
        bo[i + stride]     = pack_bins(xb, tb);
        bo[i + 2 * stride] = pack_bins(xc, tc);
        bo[i + 3 * stride] = pack_bins(xd, td);
    }
    for (; i < spatial4; i += stride)
        bo[i] = pack_bins(x4[i], t4[i]);
}

// ---- Phase B: histogram u8 bins (16 per 16B load) ----
__global__ __launch_bounds__(TPB) void hist8_kernel(
    const u32x4* __restrict__ bins16, u32* __restrict__ g_cnt, int n16)
{
    __shared__ u32 s_cnt[4][NB];
    for (int i = threadIdx.x; i < 4 * NB; i += TPB)
        ((u32*)s_cnt)[i] = 0u;
    __syncthreads();
    u32* my = s_cnt[threadIdx.x >> 6];

    const int row = blockIdx.y;
    const u32x4* __restrict__ src = bins16 + (size_t)row * n16;
    const int stride = BPRB * TPB;
    for (int i = blockIdx.x * TPB + threadIdx.x; i < n16; i += stride) {
        u32x4 v = src[i];
        #pragma unroll
        for (int w = 0; w < 4; ++w) {
            u32 word = v[w];
            atomicAdd(&my[word & 255u], 1u);
            atomicAdd(&my[(word >> 8) & 255u], 1u);
            atomicAdd(&my[(word >> 16) & 255u], 1u);
            atomicAdd(&my[word >> 24], 1u);
        }
    }
    __syncthreads();

    u32* gc = g_cnt + (size_t)row * NB;
    for (int b = threadIdx.x; b < NB; b += TPB) {
        u32 c = s_cnt[0][b] + s_cnt[1][b] + s_cnt[2][b] + s_cnt[3][b];
        if (c) atomicAdd(&gc[b], c);
    }
}

// ---- Fallback fused hist (ws too small): R9 structure at NB=256 ----
__global__ __launch_bounds__(TPB) void fused_hist_kernel(
    const f4* __restrict__ x4g, const f4* __restrict__ t4g,
    u32* __restrict__ g_cnt, int spatial4)
{
    __shared__ u32 s_cnt[NB];
    for (int i = threadIdx.x; i < NB; i += TPB) s_cnt[i] = 0u;
    __syncthreads();

    const int row = blockIdx.y;
    const f4* __restrict__ x4 = x4g + (size_t)row * spatial4;
    const f4* __restrict__ t4 = t4g + (size_t)row * spatial4;
    const int stride = BPR * TPB;
    for (int i = blockIdx.x * TPB + threadIdx.x; i < spatial4; i += stride) {
        u32 w = pack_bins(x4[i], t4[i]);
        atomicAdd(&s_cnt[w & 255u], 1u);
        atomicAdd(&s_cnt[(w >> 8) & 255u], 1u);
        atomicAdd(&s_cnt[(w >> 16) & 255u], 1u);
        atomicAdd(&s_cnt[w >> 24], 1u);
    }
    __syncthreads();
    u32* gc = g_cnt + (size_t)row * NB;
    for (int b = threadIdx.x; b < NB; b += TPB) {
        u32 c = s_cnt[b];
        if (c) atomicAdd(&gc[b], c);
    }
}

// ---- Finalize: one thread per bin, serial suffix scan ----
__global__ __launch_bounds__(NB) void topk_finalize(
    const u32* __restrict__ g_cnt, float* __restrict__ out, long long n_keep)
{
    __shared__ unsigned long long suf[NB + 1];
    __shared__ float sufs[NB + 1];
    __shared__ u32 cnt[NB];
    __shared__ float s_row[ROWS];

    const int tid = threadIdx.x;
    const unsigned long long ul_n = (unsigned long long)n_keep;

    for (int row = 0; row < ROWS; ++row) {
        cnt[tid] = g_cnt[(size_t)row * NB + tid];
        __syncthreads();

        if (tid == 0) {
            unsigned long long run = 0; float sr = 0.0f;
            suf[NB] = 0; sufs[NB] = 0.0f;
            for (int b = NB - 1; b >= 0; --b) {
                run += cnt[b];
                sr  += (float)cnt[b] * (((float)b + 0.5f) * BINW);
                suf[b] = run; sufs[b] = sr;
            }
        }
        __syncthreads();

        if (suf[tid] >= ul_n && suf[tid + 1] < ul_n) {
            unsigned long long m = ul_n - suf[tid + 1];
            float v = ((float)tid + 0.5f) * BINW;
            s_row[row] = (sufs[tid + 1] + (float)m * v) / (float)ul_n;
        }
        if (tid == 0 && suf[0] < ul_n)            // degenerate fallback
            s_row[row] = sufs[0] / (float)ul_n;
        __syncthreads();
    }

    if (tid == 0) {
        float acc = 0.0f;
        for (int r = 0; r < ROWS; ++r) acc += s_row[r];
        out[0] = acc / (float)ROWS;
    }
}

extern "C" void kernel_launch(void* const* d_in, const int* in_sizes, int n_in,
                              void* d_out, int out_size, void* d_ws, size_t ws_size,
                              hipStream_t stream) {
    const float* x = (const float*)d_in[0];   // net_output (logits)
    const float* t = (const float*)d_in[1];   // target
    float* out = (float*)d_out;

    const long long total   = (long long)in_sizes[0];           // 25,165,824
    const long long spatial = total / ROWS;                     // 12,582,912
    const long long n_keep  = llround((double)spatial * 0.10);  // 1,258,291
    const int spatial4 = (int)(spatial / 4);
    const int n16 = spatial4 / 4;

    const size_t bins_bytes = (size_t)ROWS * spatial4 * sizeof(u32);  // ~25 MB
    const size_t cnt_bytes  = (size_t)ROWS * NB * sizeof(u32);        // 2 KB

    if (ws_size >= bins_bytes + cnt_bytes) {
        u32* bins  = (u32*)d_ws;
        u32* g_cnt = (u32*)((char*)d_ws + bins_bytes);
        // ws is NOT re-poisoned between replays; zero only the counters
        // (bins are fully overwritten by phase A every call).
        (void)hipMemsetAsync(g_cnt, 0, cnt_bytes, stream);

        binize_kernel<<<dim3(BPR, ROWS), TPB, 0, stream>>>(
            (const f4*)x, (const f4*)t, bins, spatial4);
        hist8_kernel<<<dim3(BPRB, ROWS), TPB, 0, stream>>>(
            (const u32x4*)bins, g_cnt, n16);
        topk_finalize<<<1, NB, 0, stream>>>(g_cnt, out, n_keep);
    } else {
        u32* g_cnt = (u32*)d_ws;
        (void)hipMemsetAsync(g_cnt, 0, cnt_bytes, stream);
        fused_hist_kernel<<<dim3(BPR, ROWS), TPB, 0, stream>>>(
            (const f4*)x, (const f4*)t, g_cnt, spatial4);
        topk_finalize<<<1, NB, 0, stream>>>(g_cnt, out, n_keep);
    }
}

// Round 11
// 70.622 us; speedup vs baseline: 1.1954x; 1.1954x over previous
//
#include <hip/hip_runtime.h>
#include <math.h>

// BCE-with-logits + top-10% mean, shape (2,1,192,256,256) fp32.
// R11: PATH TEST — stage x,t through LDS via __builtin_amdgcn_global_load_lds
// (async DMA, bypasses the VGPR load-return path that has been pinned at
// ~4 B/cyc/CU across 9 structural variants). Per-wave-private double-buffered
// staging (no barriers), explicit vmcnt discipline. NB=1024 bins,
// bin-center error <= 3.9e-3 << 3.08e-2 threshold.

typedef float f4 __attribute__((ext_vector_type(4)));

#define NB 1024
#define ROWS 2
#define RANGE 8.0f
#define INV_BINW ((float)NB / RANGE)
#define BINW (RANGE / (float)NB)
#define TPB 256
#define BPR 1024           // blocks per row (grid 2048 = 8/CU)

#define AS1 __attribute__((address_space(1)))
#define AS3 __attribute__((address_space(3)))

__device__ __forceinline__ void hist4(const f4 xv, const f4 tv,
                                      unsigned int* __restrict__ s_cnt) {
    #pragma unroll
    for (int j = 0; j < 4; ++j) {
        float xs = xv[j], ts = tv[j];
        float l = __logf(1.0f + __expf(xs)) - xs * ts;   // loss >= 0
        atomicAdd(&s_cnt[min((int)(l * INV_BINW), NB - 1)], 1u);
    }
}

// DMA-staged histogram: requires spatial4 % (BPR*TPB) == 0 (true for real shape).
__global__ __launch_bounds__(TPB) void hist_dma_kernel(
    const f4* __restrict__ x4g, const f4* __restrict__ t4g,
    unsigned int* __restrict__ g_cnt, int spatial4)
{
    __shared__ f4 s_stage[2][2][TPB];    // [buf][stream][tid], 16 KB
    __shared__ unsigned int s_cnt[NB];   // 4 KB
    for (int i = threadIdx.x; i < NB; i += TPB) s_cnt[i] = 0u;
    __syncthreads();

    const int tid = threadIdx.x;
    const int wave = tid >> 6;
    const int row = blockIdx.y;
    const f4* __restrict__ x4 = x4g + (size_t)row * spatial4;
    const f4* __restrict__ t4 = t4g + (size_t)row * spatial4;

    const int stride = BPR * TPB;
    const int nIter = spatial4 / stride;          // 12 for the real shape
    int i = blockIdx.x * TPB + tid;

    // wave-uniform LDS destinations (HW writes base + lane*16 -> slot [tid])
    f4* sx0 = &s_stage[0][0][wave * 64];
    f4* st0 = &s_stage[0][1][wave * 64];
    f4* sx1 = &s_stage[1][0][wave * 64];
    f4* st1 = &s_stage[1][1][wave * 64];

#define STAGE(SX, ST, IDX) do {                                            \
    __builtin_amdgcn_global_load_lds((const AS1 void*)&x4[(IDX)],          \
                                     (AS3 void*)(SX), 16, 0, 0);           \
    __builtin_amdgcn_global_load_lds((const AS1 void*)&t4[(IDX)],          \
                                     (AS3 void*)(ST), 16, 0, 0);           \
} while (0)

    STAGE(sx0, st0, i);
    int b = 0;
    for (int k = 0; k < nIter - 1; ++k) {
        if (b == 0) STAGE(sx1, st1, i + stride);
        else        STAGE(sx0, st0, i + stride);
        // wait for current buf's 2 DMA loads (2 newer ones outstanding)
        asm volatile("s_waitcnt vmcnt(2)" ::: "memory");
        f4 xv = s_stage[b][0][tid];
        f4 tv = s_stage[b][1][tid];
        hist4(xv, tv, s_cnt);
        b ^= 1;
        i += stride;
    }
    asm volatile("s_waitcnt vmcnt(0)" ::: "memory");
    {
        f4 xv = s_stage[b][0][tid];
        f4 tv = s_stage[b][1][tid];
        hist4(xv, tv, s_cnt);
    }
    __syncthreads();

    unsigned int* gc = g_cnt + (size_t)row * NB;
    for (int bb = threadIdx.x; bb < NB; bb += TPB) {
        unsigned int c = s_cnt[bb];
        if (c) atomicAdd(&gc[bb], c);
    }
#undef STAGE
}

// Fallback (general shapes): R9 structure.
__global__ __launch_bounds__(TPB) void hist_kernel(
    const f4* __restrict__ x4g, const f4* __restrict__ t4g,
    unsigned int* __restrict__ g_cnt, int spatial4)
{
    __shared__ unsigned int s_cnt[NB];
    for (int i = threadIdx.x; i < NB; i += TPB) s_cnt[i] = 0u;
    __syncthreads();

    const int row = blockIdx.y;
    const f4* __restrict__ x4 = x4g + (size_t)row * spatial4;
    const f4* __restrict__ t4 = t4g + (size_t)row * spatial4;
    const int stride = BPR * TPB;
    for (int i = blockIdx.x * TPB + threadIdx.x; i < spatial4; i += stride) {
        f4 xv = x4[i], tv = t4[i];
        hist4(xv, tv, s_cnt);
    }
    __syncthreads();
    unsigned int* gc = g_cnt + (size_t)row * NB;
    for (int b = threadIdx.x; b < NB; b += TPB) {
        unsigned int c = s_cnt[b];
        if (c) atomicAdd(&gc[b], c);
    }
}

__global__ __launch_bounds__(TPB) void topk_finalize(
    const unsigned int* __restrict__ g_cnt, float* __restrict__ out,
    long long n_keep)
{
    const int BPT = NB / TPB;  // 4 bins per thread
    __shared__ unsigned long long s_cntPart[TPB];
    __shared__ float              s_sumPart[TPB];
    __shared__ unsigned long long s_cntSuf[TPB + 1];
    __shared__ float              s_sumSuf[TPB + 1];
    __shared__ float              s_row[ROWS];

    const int tid = threadIdx.x;
    const unsigned long long ul_n = (unsigned long long)n_keep;

    for (int row = 0; row < ROWS; ++row) {
        const unsigned int* gc = g_cnt + (size_t)row * NB;

        unsigned long long csum = 0; float ssum = 0.0f;
        for (int j = 0; j < BPT; ++j) {
            int b = tid * BPT + j;
            unsigned int c = gc[b];
            csum += c;
            ssum += (float)c * (((float)b + 0.5f) * BINW);
        }
        s_cntPart[tid] = csum;
        s_sumPart[tid] = ssum;
        __syncthreads();

        if (tid == 0) {
            unsigned long long run = 0; float sr = 0.0f;
            s_cntSuf[TPB] = 0; s_sumSuf[TPB] = 0.0f;
            for (int u = TPB - 1; u >= 0; --u) {
                run += s_cntPart[u]; sr += s_sumPart[u];
                s_cntSuf[u] = run;   s_sumSuf[u] = sr;
            }
        }
        __syncthreads();

        if (s_cntSuf[tid] >= ul_n && s_cntSuf[tid + 1] < ul_n) {
            unsigned long long run = s_cntSuf[tid + 1];   // count strictly above
            float srun = s_sumSuf[tid + 1];               // center-sum strictly above
            int bsel = tid * BPT;
            for (int j = BPT - 1; j >= 0; --j) {
                int b = tid * BPT + j;
                unsigned int c = gc[b];
                if (run + c >= ul_n) { bsel = b; break; }
                run += c;
                srun += (float)c * (((float)b + 0.5f) * BINW);
            }
            unsigned long long m = ul_n - run;
            float v = ((float)bsel + 0.5f) * BINW;
            s_row[row] = (srun + (float)m * v) / (float)ul_n;
        }
        if (tid == 0 && s_cntSuf[0] < ul_n) {   // degenerate fallback
            s_row[row] = s_sumSuf[0] / (float)ul_n;
        }
        __syncthreads();
    }

    if (tid == 0) {
        float acc = 0.0f;
        for (int r = 0; r < ROWS; ++r) acc += s_row[r];
        out[0] = acc / (float)ROWS;
    }
}

extern "C" void kernel_launch(void* const* d_in, const int* in_sizes, int n_in,
                              void* d_out, int out_size, void* d_ws, size_t ws_size,
                              hipStream_t stream) {
    const float* x = (const float*)d_in[0];   // net_output (logits)
    const float* t = (const float*)d_in[1];   // target
    float* out = (float*)d_out;

    const long long total   = (long long)in_sizes[0];           // 25,165,824
    const long long spatial = total / ROWS;                     // 12,582,912
    const long long n_keep  = llround((double)spatial * 0.10);  // 1,258,291
    const int spatial4 = (int)(spatial / 4);

    unsigned int* g_cnt = (unsigned int*)d_ws;
    const size_t hist_bytes = (size_t)ROWS * NB * sizeof(unsigned int);  // 8 KB

    // ws is NOT re-poisoned between replays; zero the histogram every call.
    (void)hipMemsetAsync(d_ws, 0, hist_bytes, stream);

    if ((spatial % 4) == 0 && (spatial4 % (BPR * TPB)) == 0) {
        hist_dma_kernel<<<dim3(BPR, ROWS), TPB, 0, stream>>>(
            (const f4*)x, (const f4*)t, g_cnt, spatial4);
    } else {
        hist_kernel<<<dim3(BPR, ROWS), TPB, 0, stream>>>(
            (const f4*)x, (const f4*)t, g_cnt, spatial4);
    }
    topk_finalize<<<1, TPB, 0, stream>>>(g_cnt, out, n_keep);
}